// Round 8
// baseline (689.953 us; speedup 1.0000x reference)
//
#include <hip/hip_runtime.h>

typedef float v2f __attribute__((ext_vector_type(2)));

#define T_LEN 512
#define INP 5
#define HID 32

__device__ __forceinline__ v2f pkfma(v2f a, v2f b, v2f c) {
    return __builtin_elementwise_fma(a, b, c);
}

// 2-wave pipelined split per batch element (128 threads):
//   waveA (wid 0): layer-0 LSTM cell for t=s     (Whh0 rows + Wih0 row in regs)
//   waveB (wid 1): layer-1 LSTM cell for t=s-1   (Wih1 + Whh1 rows in regs)
// One __syncthreads per step; h0 passes A->B via a 2-slot LDS ring.
// Each layer's accumulation DAG is verbatim R6 (bit-exact, absmax 0.0).
__global__ __launch_bounds__(128, 2) void lstm2_2wpipe(
    const float* __restrict__ x,
    const float* __restrict__ Wih0, const float* __restrict__ Whh0,
    const float* __restrict__ bih0, const float* __restrict__ bhh0,
    const float* __restrict__ Wih1, const float* __restrict__ Whh1,
    const float* __restrict__ bih1, const float* __restrict__ bhh1,
    const float* __restrict__ Wfc,  const float* __restrict__ bfc,
    float* __restrict__ out)
{
    const int b   = blockIdx.x;
    const int tid = threadIdx.x;
    const int wid = tid >> 6;          // 0 = waveA (L0), 1 = waveB (L1)
    const int l   = tid & 63;
    const int glo = l, ghi = l + 64;   // this lane's two gate rows (of 128)
    const bool isIG = (l < 32);        // lanes<32: (i,g); lanes>=32: (f,o)

    __shared__ __align__(16) float xs[T_LEN][8];     // 16 KB staged input
    __shared__ __align__(16) float h0ring[2][HID];   // A -> B ring
    __shared__ __align__(16) float h1s[HID];         // B-internal

    // ---- stage x[b] into LDS (both waves), init states ----
    const float* xb = x + (size_t)b * (T_LEN * INP);
    for (int idx = tid; idx < T_LEN * INP; idx += 128) {
        const int t = idx / INP;
        const int d = idx - t * INP;
        xs[t][d] = xb[idx];
    }
    if (tid < HID) { h0ring[1][tid] = 0.0f; h1s[tid] = 0.0f; }

    // ---- per-wave weight rows: A: w1=Whh0 (w2 dup, unused); B: w1=Wih1, w2=Whh1 ----
    const float* M1 = wid ? Wih1 : Whh0;
    const float* M2 = wid ? Whh1 : Whh0;
    v2f w1lo[16], w1hi[16], w2lo[16], w2hi[16];
    {
        const v2f* a_ = (const v2f*)(M1 + glo * HID);
        const v2f* b_ = (const v2f*)(M1 + ghi * HID);
        const v2f* c_ = (const v2f*)(M2 + glo * HID);
        const v2f* d_ = (const v2f*)(M2 + ghi * HID);
        #pragma unroll
        for (int q = 0; q < 16; ++q) {
            w1lo[q] = a_[q]; w1hi[q] = b_[q];
            w2lo[q] = c_[q]; w2hi[q] = d_[q];
        }
    }

    // layer-0 input weights (used by A only; loaded uniformly)
    v2f wxlo01, wxlo23, wxhi01, wxhi23;
    float wxlo4, wxhi4;
    {
        const float* rl = Wih0 + glo * INP;
        const float* rh = Wih0 + ghi * INP;
        wxlo01 = (v2f){rl[0], rl[1]}; wxlo23 = (v2f){rl[2], rl[3]}; wxlo4 = rl[4];
        wxhi01 = (v2f){rh[0], rh[1]}; wxhi23 = (v2f){rh[2], rh[3]}; wxhi4 = rh[4];
    }

    const float bias_lo = wid ? (bih1[glo] + bhh1[glo]) : (bih0[glo] + bhh0[glo]);
    const float bias_hi = wid ? (bih1[ghi] + bhh1[ghi]) : (bih0[ghi] + bhh0[ghi]);

    // activations: sigmoid(v) = rcp(1+exp2(-log2e*v)); tanh(v) = 2*rcp(1+exp2(-2log2e*v))-1
    const float NL2E  = -1.4426950408889634f;
    const float NL2E2 = -2.8853900817779268f;
    const float kk_hi = isIG ? NL2E2 : NL2E;    // g: tanh, o: sigmoid
    const float sc_hi = isIG ?  2.0f : 1.0f;
    const float bb_hi = isIG ? -1.0f : 0.0f;

    float cst = 0.0f;     // c0 (A) / c1 (B)
    float h1last = 0.0f;  // B: running h1

    __syncthreads();

#define RED(a0, a1) ({ v2f s_ = (a0) + (a1); s_.x + s_.y; })

    for (int s = 0; s <= T_LEN; ++s) {
        if (wid == 0) {
            // ================= waveA: layer-0 cell, t = s =================
            if (s < T_LEN) {
                v2f xv01 = *(const v2f*)&xs[s][0];
                v2f xv23 = *(const v2f*)&xs[s][2];
                float x4 = xs[s][4];

                v2f aL0 = pkfma(wxlo01, xv01, (v2f){bias_lo, 0.0f});
                v2f aL1 = pkfma(wxlo23, xv23, (v2f){wxlo4 * x4, 0.0f});
                v2f aH0 = pkfma(wxhi01, xv01, (v2f){bias_hi, 0.0f});
                v2f aH1 = pkfma(wxhi23, xv23, (v2f){wxhi4 * x4, 0.0f});
                const v2f* h02 = (const v2f*)h0ring[(s + 1) & 1];   // h0_{s-1}
                #pragma unroll
                for (int r = 0; r < 8; ++r) {
                    v2f hp0 = h02[2*r];
                    v2f hp1 = h02[2*r+1];
                    aL0 = pkfma(w1lo[2*r],   hp0, aL0);
                    aL1 = pkfma(w1lo[2*r+1], hp1, aL1);
                    aH0 = pkfma(w1hi[2*r],   hp0, aH0);
                    aH1 = pkfma(w1hi[2*r+1], hp1, aH1);
                }
                float gl = RED(aL0, aL1);
                float gh = RED(aH0, aH1);

                float actL = __builtin_amdgcn_rcpf(1.0f + exp2f(NL2E * gl));
                float actH = fmaf(sc_hi, __builtin_amdgcn_rcpf(1.0f + exp2f(kk_hi * gh)), bb_hi);
                float actLs = __shfl_xor(actL, 32);
                float actHs = __shfl_xor(actH, 32);
                float i_ = isIG ? actL  : actLs;
                float f_ = isIG ? actLs : actL;
                float g_ = isIG ? actH  : actHs;
                float o_ = isIG ? actHs : actH;
                cst = fmaf(f_, cst, i_ * g_);
                float th = fmaf(2.0f, __builtin_amdgcn_rcpf(1.0f + exp2f(NL2E2 * cst)), -1.0f);
                float h0new = o_ * th;
                h0ring[s & 1][l & 31] = h0new;   // dup lanes write identical value
            }
        } else {
            // ================= waveB: layer-1 cell, t = s-1 =================
            if (s >= 1) {
                const v2f* h02 = (const v2f*)h0ring[(s + 1) & 1];   // h0_{s-1} (fresh for t)
                const v2f* h12 = (const v2f*)h1s;                    // h1_{t-1}

                v2f bL0 = (v2f){bias_lo, 0.0f}, bL1 = (v2f)0.0f;
                v2f bH0 = (v2f){bias_hi, 0.0f}, bH1 = (v2f)0.0f;
                #pragma unroll
                for (int r = 0; r < 8; ++r) {
                    v2f hp0 = h02[2*r];
                    v2f hp1 = h02[2*r+1];
                    bL0 = pkfma(w1lo[2*r],   hp0, bL0);
                    bL1 = pkfma(w1lo[2*r+1], hp1, bL1);
                    bH0 = pkfma(w1hi[2*r],   hp0, bH0);
                    bH1 = pkfma(w1hi[2*r+1], hp1, bH1);
                }
                #pragma unroll
                for (int r = 0; r < 8; ++r) {
                    v2f hp0 = h12[2*r];
                    v2f hp1 = h12[2*r+1];
                    bL0 = pkfma(w2lo[2*r],   hp0, bL0);
                    bL1 = pkfma(w2lo[2*r+1], hp1, bL1);
                    bH0 = pkfma(w2hi[2*r],   hp0, bH0);
                    bH1 = pkfma(w2hi[2*r+1], hp1, bH1);
                }
                float gl = RED(bL0, bL1);
                float gh = RED(bH0, bH1);

                float actL = __builtin_amdgcn_rcpf(1.0f + exp2f(NL2E * gl));
                float actH = fmaf(sc_hi, __builtin_amdgcn_rcpf(1.0f + exp2f(kk_hi * gh)), bb_hi);
                float actLs = __shfl_xor(actL, 32);
                float actHs = __shfl_xor(actH, 32);
                float i_ = isIG ? actL  : actLs;
                float f_ = isIG ? actLs : actL;
                float g_ = isIG ? actH  : actHs;
                float o_ = isIG ? actHs : actH;
                cst = fmaf(f_, cst, i_ * g_);
                float th = fmaf(2.0f, __builtin_amdgcn_rcpf(1.0f + exp2f(NL2E2 * cst)), -1.0f);
                h1last = o_ * th;
                h1s[l & 31] = h1last;            // read-before-write within step; in-order
            }
        }
        __syncthreads();
    }
#undef RED

    // ---- final linear head: waveB holds h1_{T-1} ----
    if (wid == 1) {
        const int m = l & 31;
        float p0 = isIG ? (Wfc[m]       * h1last) : 0.0f;
        float p1 = isIG ? (Wfc[HID + m] * h1last) : 0.0f;
        #pragma unroll
        for (int off = 32; off >= 1; off >>= 1) {
            p0 += __shfl_xor(p0, off);
            p1 += __shfl_xor(p1, off);
        }
        if (l == 0) {
            out[2 * b + 0] = p0 + bfc[0];
            out[2 * b + 1] = p1 + bfc[1];
        }
    }
}

extern "C" void kernel_launch(void* const* d_in, const int* in_sizes, int n_in,
                              void* d_out, int out_size, void* d_ws, size_t ws_size,
                              hipStream_t stream) {
    const float* x    = (const float*)d_in[0];
    const float* Wih0 = (const float*)d_in[1];
    const float* Whh0 = (const float*)d_in[2];
    const float* bih0 = (const float*)d_in[3];
    const float* bhh0 = (const float*)d_in[4];
    const float* Wih1 = (const float*)d_in[5];
    const float* Whh1 = (const float*)d_in[6];
    const float* bih1 = (const float*)d_in[7];
    const float* bhh1 = (const float*)d_in[8];
    const float* Wfc  = (const float*)d_in[9];
    const float* bfc  = (const float*)d_in[10];
    float* out = (float*)d_out;

    const int nb = in_sizes[0] / (T_LEN * INP);   // 2048 batch elements
    lstm2_2wpipe<<<dim3(nb), dim3(128), 0, stream>>>(
        x, Wih0, Whh0, bih0, bhh0, Wih1, Whh1, bih1, bhh1, Wfc, bfc, out);
}

// Round 9
// 625.641 us; speedup vs baseline: 1.1028x; 1.1028x over previous
//
#include <hip/hip_runtime.h>

typedef float v2f __attribute__((ext_vector_type(2)));

#define T_LEN 512
#define INP 5
#define HID 32

__device__ __forceinline__ v2f pkfma(v2f a, v2f b, v2f c) {
    return __builtin_elementwise_fma(a, b, c);
}

// One wave, TWO batch elements (A,B). Weights register-resident once, used for
// both elements (amortizes register-file shuttling). Grid = 1024 single-wave
// blocks = 1 wave/SIMD on all 1024 SIMDs; latency hidden by A/B ILP, no barriers.
// Per-element arithmetic DAG is verbatim R6 (absmax 0.0).
__global__ __launch_bounds__(64, 1) void lstm2_dual(
    const float* __restrict__ x,
    const float* __restrict__ Wih0, const float* __restrict__ Whh0,
    const float* __restrict__ bih0, const float* __restrict__ bhh0,
    const float* __restrict__ Wih1, const float* __restrict__ Whh1,
    const float* __restrict__ bih1, const float* __restrict__ bhh1,
    const float* __restrict__ Wfc,  const float* __restrict__ bfc,
    float* __restrict__ out)
{
    const int bp = blockIdx.x;        // element pair: elements 2*bp, 2*bp+1
    const int l  = threadIdx.x;       // 0..63
    const int glo = l, ghi = l + 64;  // this lane's two gate rows (of 128)
    const bool isIG = (l < 32);       // lanes<32: (i,g); lanes>=32: (f,o)
    const int m = l & 31;

    __shared__ __align__(16) float xsA[T_LEN][8];   // 16 KB element A input
    __shared__ __align__(16) float xsB[T_LEN][8];   // 16 KB element B input
    __shared__ __align__(16) float hb[4][HID];      // [0]=h0A [1]=h0B [2]=h1A [3]=h1B

    // ---- stage x for both elements (single wave: in-order, no barrier) ----
    const float* xA = x + (size_t)(2 * bp)     * (T_LEN * INP);
    const float* xB = x + (size_t)(2 * bp + 1) * (T_LEN * INP);
    for (int idx = l; idx < T_LEN * INP; idx += 64) {
        const int t = idx / INP;
        const int d = idx - t * INP;
        xsA[t][d] = xA[idx];
        xsB[t][d] = xB[idx];
    }
    for (int q = l; q < 4 * HID; q += 64) ((float*)hb)[q] = 0.0f;

    // ---- weights register-resident as v2f over j-pairs (shared by A and B) ----
    v2f whh0_lo[16], whh0_hi[16], wih1_lo[16], wih1_hi[16], whh1_lo[16], whh1_hi[16];
#define LOADW(dst_lo, dst_hi, W) { \
    const v2f* rlo_ = (const v2f*)((W) + glo * HID); \
    const v2f* rhi_ = (const v2f*)((W) + ghi * HID); \
    _Pragma("unroll") \
    for (int q = 0; q < 16; ++q) { \
        dst_lo[q] = rlo_[q]; \
        dst_hi[q] = rhi_[q]; \
    } }
    LOADW(whh0_lo, whh0_hi, Whh0)
    LOADW(wih1_lo, wih1_hi, Wih1)
    LOADW(whh1_lo, whh1_hi, Whh1)
#undef LOADW

    v2f wxlo01, wxlo23, wxhi01, wxhi23;
    float wxlo4, wxhi4;
    {
        const float* rl = Wih0 + glo * INP;
        const float* rh = Wih0 + ghi * INP;
        wxlo01 = (v2f){rl[0], rl[1]}; wxlo23 = (v2f){rl[2], rl[3]}; wxlo4 = rl[4];
        wxhi01 = (v2f){rh[0], rh[1]}; wxhi23 = (v2f){rh[2], rh[3]}; wxhi4 = rh[4];
    }

    const float bias0_lo = bih0[glo] + bhh0[glo];
    const float bias0_hi = bih0[ghi] + bhh0[ghi];
    const float bias1_lo = bih1[glo] + bhh1[glo];
    const float bias1_hi = bih1[ghi] + bhh1[ghi];

    // activations: sigmoid(v) = rcp(1+exp2(-log2e*v)); tanh(v) = 2*rcp(1+exp2(-2log2e*v))-1
    const float NL2E  = -1.4426950408889634f;
    const float NL2E2 = -2.8853900817779268f;
    const float kk_hi = isIG ? NL2E2 : NL2E;    // g: tanh, o: sigmoid
    const float sc_hi = isIG ?  2.0f : 1.0f;
    const float bb_hi = isIG ? -1.0f : 0.0f;

    float cA0 = 0.0f, cA1 = 0.0f, hA1last = 0.0f;
    float cB0 = 0.0f, cB1 = 0.0f, hB1last = 0.0f;

    const v2f* h0A = (const v2f*)hb[0];
    const v2f* h0B = (const v2f*)hb[1];
    const v2f* h1A = (const v2f*)hb[2];
    const v2f* h1B = (const v2f*)hb[3];

#define RED(a0, a1) ({ v2f s_ = (a0) + (a1); s_.x + s_.y; })

    for (int t = 0; t < T_LEN; ++t) {
        // ---- x_t (uniform LDS broadcast) ----
        v2f xvA01 = *(const v2f*)&xsA[t][0];
        v2f xvA23 = *(const v2f*)&xsA[t][2];
        float xA4 = xsA[t][4];
        v2f xvB01 = *(const v2f*)&xsB[t][0];
        v2f xvB23 = *(const v2f*)&xsB[t][2];
        float xB4 = xsB[t][4];

        // ================= layer 0, elements A and B interleaved =================
        v2f aL0 = pkfma(wxlo01, xvA01, (v2f){bias0_lo, 0.0f});
        v2f aL1 = pkfma(wxlo23, xvA23, (v2f){wxlo4 * xA4, 0.0f});
        v2f aH0 = pkfma(wxhi01, xvA01, (v2f){bias0_hi, 0.0f});
        v2f aH1 = pkfma(wxhi23, xvA23, (v2f){wxhi4 * xA4, 0.0f});
        v2f eL0 = pkfma(wxlo01, xvB01, (v2f){bias0_lo, 0.0f});
        v2f eL1 = pkfma(wxlo23, xvB23, (v2f){wxlo4 * xB4, 0.0f});
        v2f eH0 = pkfma(wxhi01, xvB01, (v2f){bias0_hi, 0.0f});
        v2f eH1 = pkfma(wxhi23, xvB23, (v2f){wxhi4 * xB4, 0.0f});
        #pragma unroll
        for (int r = 0; r < 8; ++r) {
            v2f wl0 = whh0_lo[2*r], wl1 = whh0_lo[2*r+1];
            v2f wh0 = whh0_hi[2*r], wh1 = whh0_hi[2*r+1];
            v2f hpA0 = h0A[2*r], hpA1 = h0A[2*r+1];
            v2f hpB0 = h0B[2*r], hpB1 = h0B[2*r+1];
            aL0 = pkfma(wl0, hpA0, aL0);
            aL1 = pkfma(wl1, hpA1, aL1);
            aH0 = pkfma(wh0, hpA0, aH0);
            aH1 = pkfma(wh1, hpA1, aH1);
            eL0 = pkfma(wl0, hpB0, eL0);
            eL1 = pkfma(wl1, hpB1, eL1);
            eH0 = pkfma(wh0, hpB0, eH0);
            eH1 = pkfma(wh1, hpB1, eH1);
        }
        float glA = RED(aL0, aL1);
        float ghA = RED(aH0, aH1);
        float glB = RED(eL0, eL1);
        float ghB = RED(eH0, eH1);

        float actLA = __builtin_amdgcn_rcpf(1.0f + exp2f(NL2E * glA));
        float actHA = fmaf(sc_hi, __builtin_amdgcn_rcpf(1.0f + exp2f(kk_hi * ghA)), bb_hi);
        float actLB = __builtin_amdgcn_rcpf(1.0f + exp2f(NL2E * glB));
        float actHB = fmaf(sc_hi, __builtin_amdgcn_rcpf(1.0f + exp2f(kk_hi * ghB)), bb_hi);
        float actLAs = __shfl_xor(actLA, 32);
        float actHAs = __shfl_xor(actHA, 32);
        float actLBs = __shfl_xor(actLB, 32);
        float actHBs = __shfl_xor(actHB, 32);
        {
            float i_ = isIG ? actLA  : actLAs;
            float f_ = isIG ? actLAs : actLA;
            float g_ = isIG ? actHA  : actHAs;
            float o_ = isIG ? actHAs : actHA;
            cA0 = fmaf(f_, cA0, i_ * g_);
            float th = fmaf(2.0f, __builtin_amdgcn_rcpf(1.0f + exp2f(NL2E2 * cA0)), -1.0f);
            hb[0][m] = o_ * th;
        }
        {
            float i_ = isIG ? actLB  : actLBs;
            float f_ = isIG ? actLBs : actLB;
            float g_ = isIG ? actHB  : actHBs;
            float o_ = isIG ? actHBs : actHB;
            cB0 = fmaf(f_, cB0, i_ * g_);
            float th = fmaf(2.0f, __builtin_amdgcn_rcpf(1.0f + exp2f(NL2E2 * cB0)), -1.0f);
            hb[1][m] = o_ * th;
        }

        // ================= layer 1, elements A and B interleaved =================
        v2f bL0 = (v2f){bias1_lo, 0.0f}, bL1 = (v2f)0.0f;
        v2f bH0 = (v2f){bias1_hi, 0.0f}, bH1 = (v2f)0.0f;
        v2f fL0 = (v2f){bias1_lo, 0.0f}, fL1 = (v2f)0.0f;
        v2f fH0 = (v2f){bias1_hi, 0.0f}, fH1 = (v2f)0.0f;
        #pragma unroll
        for (int r = 0; r < 8; ++r) {           // Wih1 * h0_t  (fresh h0, same order as R6)
            v2f wl0 = wih1_lo[2*r], wl1 = wih1_lo[2*r+1];
            v2f wh0 = wih1_hi[2*r], wh1 = wih1_hi[2*r+1];
            v2f hpA0 = h0A[2*r], hpA1 = h0A[2*r+1];
            v2f hpB0 = h0B[2*r], hpB1 = h0B[2*r+1];
            bL0 = pkfma(wl0, hpA0, bL0);
            bL1 = pkfma(wl1, hpA1, bL1);
            bH0 = pkfma(wh0, hpA0, bH0);
            bH1 = pkfma(wh1, hpA1, bH1);
            fL0 = pkfma(wl0, hpB0, fL0);
            fL1 = pkfma(wl1, hpB1, fL1);
            fH0 = pkfma(wh0, hpB0, fH0);
            fH1 = pkfma(wh1, hpB1, fH1);
        }
        #pragma unroll
        for (int r = 0; r < 8; ++r) {           // Whh1 * h1_{t-1}
            v2f wl0 = whh1_lo[2*r], wl1 = whh1_lo[2*r+1];
            v2f wh0 = whh1_hi[2*r], wh1 = whh1_hi[2*r+1];
            v2f hpA0 = h1A[2*r], hpA1 = h1A[2*r+1];
            v2f hpB0 = h1B[2*r], hpB1 = h1B[2*r+1];
            bL0 = pkfma(wl0, hpA0, bL0);
            bL1 = pkfma(wl1, hpA1, bL1);
            bH0 = pkfma(wh0, hpA0, bH0);
            bH1 = pkfma(wh1, hpA1, bH1);
            fL0 = pkfma(wl0, hpB0, fL0);
            fL1 = pkfma(wl1, hpB1, fL1);
            fH0 = pkfma(wh0, hpB0, fH0);
            fH1 = pkfma(wh1, hpB1, fH1);
        }
        float glA1 = RED(bL0, bL1);
        float ghA1 = RED(bH0, bH1);
        float glB1 = RED(fL0, fL1);
        float ghB1 = RED(fH0, fH1);

        float actLA1 = __builtin_amdgcn_rcpf(1.0f + exp2f(NL2E * glA1));
        float actHA1 = fmaf(sc_hi, __builtin_amdgcn_rcpf(1.0f + exp2f(kk_hi * ghA1)), bb_hi);
        float actLB1 = __builtin_amdgcn_rcpf(1.0f + exp2f(NL2E * glB1));
        float actHB1 = fmaf(sc_hi, __builtin_amdgcn_rcpf(1.0f + exp2f(kk_hi * ghB1)), bb_hi);
        float actLA1s = __shfl_xor(actLA1, 32);
        float actHA1s = __shfl_xor(actHA1, 32);
        float actLB1s = __shfl_xor(actLB1, 32);
        float actHB1s = __shfl_xor(actHB1, 32);
        {
            float i_ = isIG ? actLA1  : actLA1s;
            float f_ = isIG ? actLA1s : actLA1;
            float g_ = isIG ? actHA1  : actHA1s;
            float o_ = isIG ? actHA1s : actHA1;
            cA1 = fmaf(f_, cA1, i_ * g_);
            float th = fmaf(2.0f, __builtin_amdgcn_rcpf(1.0f + exp2f(NL2E2 * cA1)), -1.0f);
            hA1last = o_ * th;
            hb[2][m] = hA1last;
        }
        {
            float i_ = isIG ? actLB1  : actLB1s;
            float f_ = isIG ? actLB1s : actLB1;
            float g_ = isIG ? actHB1  : actHB1s;
            float o_ = isIG ? actHB1s : actHB1;
            cB1 = fmaf(f_, cB1, i_ * g_);
            float th = fmaf(2.0f, __builtin_amdgcn_rcpf(1.0f + exp2f(NL2E2 * cB1)), -1.0f);
            hB1last = o_ * th;
            hb[3][m] = hB1last;
        }
    }
#undef RED

    // ---- final linear heads ----
    float p0 = isIG ? (Wfc[m]       * hA1last) : 0.0f;
    float p1 = isIG ? (Wfc[HID + m] * hA1last) : 0.0f;
    float q0 = isIG ? (Wfc[m]       * hB1last) : 0.0f;
    float q1 = isIG ? (Wfc[HID + m] * hB1last) : 0.0f;
    #pragma unroll
    for (int off = 32; off >= 1; off >>= 1) {
        p0 += __shfl_xor(p0, off);
        p1 += __shfl_xor(p1, off);
        q0 += __shfl_xor(q0, off);
        q1 += __shfl_xor(q1, off);
    }
    if (l == 0) {
        out[2 * (2 * bp)     + 0] = p0 + bfc[0];
        out[2 * (2 * bp)     + 1] = p1 + bfc[1];
        out[2 * (2 * bp + 1) + 0] = q0 + bfc[0];
        out[2 * (2 * bp + 1) + 1] = q1 + bfc[1];
    }
}

extern "C" void kernel_launch(void* const* d_in, const int* in_sizes, int n_in,
                              void* d_out, int out_size, void* d_ws, size_t ws_size,
                              hipStream_t stream) {
    const float* x    = (const float*)d_in[0];
    const float* Wih0 = (const float*)d_in[1];
    const float* Whh0 = (const float*)d_in[2];
    const float* bih0 = (const float*)d_in[3];
    const float* bhh0 = (const float*)d_in[4];
    const float* Wih1 = (const float*)d_in[5];
    const float* Whh1 = (const float*)d_in[6];
    const float* bih1 = (const float*)d_in[7];
    const float* bhh1 = (const float*)d_in[8];
    const float* Wfc  = (const float*)d_in[9];
    const float* bfc  = (const float*)d_in[10];
    float* out = (float*)d_out;

    const int nb = in_sizes[0] / (T_LEN * INP);   // 2048 batch elements
    lstm2_dual<<<dim3(nb / 2), dim3(64), 0, stream>>>(
        x, Wih0, Whh0, bih0, bhh0, Wih1, Whh1, bih1, bhh1, Wfc, bfc, out);
}